// Round 10
// baseline (462.830 us; speedup 1.0000x reference)
//
#include <hip/hip_runtime.h>
#include <hip/hip_bf16.h>

#define N_NODES 50000
#define E_EDGES 1000000
#define FIN 512
#define FOUT 128

// bucketed CSR: 128 rows per coarse bucket
#define BROWS 128
#define NB 391            // ceil(50000/128) buckets per support
#define NB2 782           // both supports

__device__ __forceinline__ float bf2f(unsigned short u) {
    unsigned int x = ((unsigned int)u) << 16;
    return __builtin_bit_cast(float, x);
}
__device__ __forceinline__ unsigned short f2bf(float f) {
    unsigned int x = __builtin_bit_cast(unsigned int, f);
    unsigned int r = x + 0x7fffu + ((x >> 16) & 1u);  // RNE
    return (unsigned short)(r >> 16);
}

// ---------------------------------------------------------------- dtype detection
__global__ void detect_kernel(const unsigned int* __restrict__ xraw,
                              const unsigned int* __restrict__ idxraw,
                              int* __restrict__ flags) {
    __shared__ int cnt, odd_nz;
    const int t = threadIdx.x;
    if (t == 0) { cnt = 0; odd_nz = 0; }
    __syncthreads();
    int local = 0;
    for (int i = t; i < 1024; i += 256) {
        unsigned int b = (xraw[i] >> 7) & 0xFF;   // bits 14..7 = low-half bf16 exponent field
        if (b >= 115 && b <= 133) local++;
    }
    atomicAdd(&cnt, local);
    if (t < 128) {
        if (idxraw[2 * t + 1] != 0u) atomicAdd(&odd_nz, 1);
    }
    __syncthreads();
    if (t == 0) {
        flags[0] = (cnt < 512) ? 1 : 0;   // 1 => floats are f32
        flags[1] = (odd_nz == 0) ? 1 : 0; // 1 => indices are int64
    }
}

// ---------------------------------------------------------------- zero helper
__global__ void zero_kernel(float4* __restrict__ p, int n4) {
    int i = blockIdx.x * blockDim.x + threadIdx.x;
    int stride = gridDim.x * blockDim.x;
    for (; i < n4; i += stride) p[i] = make_float4(0.f, 0.f, 0.f, 0.f);
}

// ---------------------------------------------------------------- GEMM: pre = x @ W, 4x4 register-blocked VALU, dtype-adaptive
// W-staging writes float4 index (tid + 256*j): conflict-free (round-7 fix).
// Inner loop processes k in chunks of 4 with b128 LDS reads for BOTH
// operands (round-9 fix): per chunk 8 ds_read_b128 (~96cyc LDS issue)
// feeds 64 FMAs (~128cyc VALU) -> VALU-bound (was 1xb128+4xb32 per k:
// ~35cyc LDS vs 32cyc FMA -> LDS-pipe throttled at ~50%).
#define GBR 32
#define GKT 64
#define SXS 68
__global__ __launch_bounds__(256) void gemm_kernel(const void* __restrict__ xv,
                                                   const void* __restrict__ Wv,
                                                   float* __restrict__ pre,
                                                   const int* __restrict__ flags) {
    __shared__ float sx[GBR * SXS];   // 8.5 KB
    __shared__ float sw[GKT * FOUT];  // 32 KB

    const int tid  = threadIdx.x;
    const int f32m = flags[0];
    const int r0   = blockIdx.x * GBR;

    const int cg  = tid & 31;         // col group -> 4 cols
    const int rg  = tid >> 5;         // row group 0..7 -> 4 rows
    const int c0  = cg * 4;
    const int rl0 = rg * 4;

    const int lrow  = tid >> 3;           // 0..31
    const int kbase = (tid & 7) * 8;      // 0..56
    int grow = r0 + lrow;
    if (grow >= N_NODES) grow = N_NODES - 1;   // clamp; store is guarded

    float acc[4][4];
#pragma unroll
    for (int j = 0; j < 4; j++)
#pragma unroll
        for (int i = 0; i < 4; i++) acc[j][i] = 0.f;

    for (int kt = 0; kt < FIN; kt += GKT) {
        // ---- stage x tile (32 rows x 64 k)
        if (f32m) {
            const float* xf = (const float*)xv + (size_t)grow * FIN + kt + kbase;
            float4 a = ((const float4*)xf)[0];
            float4 b = ((const float4*)xf)[1];
            *(float4*)&sx[lrow * SXS + kbase]     = a;
            *(float4*)&sx[lrow * SXS + kbase + 4] = b;
        } else {
            const ushort* xh = (const ushort*)xv + (size_t)grow * FIN + kt + kbase;
            ushort tmp[8];
            *(uint4*)tmp = *(const uint4*)xh;
#pragma unroll
            for (int j = 0; j < 8; j++) sx[lrow * SXS + kbase + j] = bf2f(tmp[j]);
        }
        // ---- stage W tile (64 k x 128 cols), conflict-free pattern
        if (f32m) {
            const float4* wf = (const float4*)((const float*)Wv + (size_t)kt * FOUT);
#pragma unroll
            for (int j = 0; j < 8; j++)
                ((float4*)sw)[tid + 256 * j] = wf[tid + 256 * j];
        } else {
            const ushort* wh = (const ushort*)Wv + (size_t)kt * FOUT;
#pragma unroll
            for (int j = 0; j < 8; j++) {
                const int m = tid + 256 * j;          // float4 index
                ushort4 t4 = *(const ushort4*)(wh + 4 * m);
                float4 o;
                o.x = bf2f(t4.x); o.y = bf2f(t4.y);
                o.z = bf2f(t4.z); o.w = bf2f(t4.w);
                ((float4*)sw)[m] = o;
            }
        }
        __syncthreads();

#pragma unroll 2
        for (int kq = 0; kq < GKT / 4; kq++) {
            const int k4 = kq * 4;
            const float4 w0 = *(const float4*)&sw[(k4 + 0) * FOUT + c0];
            const float4 w1 = *(const float4*)&sw[(k4 + 1) * FOUT + c0];
            const float4 w2 = *(const float4*)&sw[(k4 + 2) * FOUT + c0];
            const float4 w3 = *(const float4*)&sw[(k4 + 3) * FOUT + c0];
            const float4 x0 = *(const float4*)&sx[(rl0 + 0) * SXS + k4];
            const float4 x1 = *(const float4*)&sx[(rl0 + 1) * SXS + k4];
            const float4 x2 = *(const float4*)&sx[(rl0 + 2) * SXS + k4];
            const float4 x3 = *(const float4*)&sx[(rl0 + 3) * SXS + k4];
            // dk = 0 (k ascending per accumulator: bit-identical to rolled loop)
            acc[0][0] = fmaf(x0.x, w0.x, acc[0][0]); acc[0][1] = fmaf(x0.x, w0.y, acc[0][1]);
            acc[0][2] = fmaf(x0.x, w0.z, acc[0][2]); acc[0][3] = fmaf(x0.x, w0.w, acc[0][3]);
            acc[1][0] = fmaf(x1.x, w0.x, acc[1][0]); acc[1][1] = fmaf(x1.x, w0.y, acc[1][1]);
            acc[1][2] = fmaf(x1.x, w0.z, acc[1][2]); acc[1][3] = fmaf(x1.x, w0.w, acc[1][3]);
            acc[2][0] = fmaf(x2.x, w0.x, acc[2][0]); acc[2][1] = fmaf(x2.x, w0.y, acc[2][1]);
            acc[2][2] = fmaf(x2.x, w0.z, acc[2][2]); acc[2][3] = fmaf(x2.x, w0.w, acc[2][3]);
            acc[3][0] = fmaf(x3.x, w0.x, acc[3][0]); acc[3][1] = fmaf(x3.x, w0.y, acc[3][1]);
            acc[3][2] = fmaf(x3.x, w0.z, acc[3][2]); acc[3][3] = fmaf(x3.x, w0.w, acc[3][3]);
            // dk = 1
            acc[0][0] = fmaf(x0.y, w1.x, acc[0][0]); acc[0][1] = fmaf(x0.y, w1.y, acc[0][1]);
            acc[0][2] = fmaf(x0.y, w1.z, acc[0][2]); acc[0][3] = fmaf(x0.y, w1.w, acc[0][3]);
            acc[1][0] = fmaf(x1.y, w1.x, acc[1][0]); acc[1][1] = fmaf(x1.y, w1.y, acc[1][1]);
            acc[1][2] = fmaf(x1.y, w1.z, acc[1][2]); acc[1][3] = fmaf(x1.y, w1.w, acc[1][3]);
            acc[2][0] = fmaf(x2.y, w1.x, acc[2][0]); acc[2][1] = fmaf(x2.y, w1.y, acc[2][1]);
            acc[2][2] = fmaf(x2.y, w1.z, acc[2][2]); acc[2][3] = fmaf(x2.y, w1.w, acc[2][3]);
            acc[3][0] = fmaf(x3.y, w1.x, acc[3][0]); acc[3][1] = fmaf(x3.y, w1.y, acc[3][1]);
            acc[3][2] = fmaf(x3.y, w1.z, acc[3][2]); acc[3][3] = fmaf(x3.y, w1.w, acc[3][3]);
            // dk = 2
            acc[0][0] = fmaf(x0.z, w2.x, acc[0][0]); acc[0][1] = fmaf(x0.z, w2.y, acc[0][1]);
            acc[0][2] = fmaf(x0.z, w2.z, acc[0][2]); acc[0][3] = fmaf(x0.z, w2.w, acc[0][3]);
            acc[1][0] = fmaf(x1.z, w2.x, acc[1][0]); acc[1][1] = fmaf(x1.z, w2.y, acc[1][1]);
            acc[1][2] = fmaf(x1.z, w2.z, acc[1][2]); acc[1][3] = fmaf(x1.z, w2.w, acc[1][3]);
            acc[2][0] = fmaf(x2.z, w2.x, acc[2][0]); acc[2][1] = fmaf(x2.z, w2.y, acc[2][1]);
            acc[2][2] = fmaf(x2.z, w2.z, acc[2][2]); acc[2][3] = fmaf(x2.z, w2.w, acc[2][3]);
            acc[3][0] = fmaf(x3.z, w2.x, acc[3][0]); acc[3][1] = fmaf(x3.z, w2.y, acc[3][1]);
            acc[3][2] = fmaf(x3.z, w2.z, acc[3][2]); acc[3][3] = fmaf(x3.z, w2.w, acc[3][3]);
            // dk = 3
            acc[0][0] = fmaf(x0.w, w3.x, acc[0][0]); acc[0][1] = fmaf(x0.w, w3.y, acc[0][1]);
            acc[0][2] = fmaf(x0.w, w3.z, acc[0][2]); acc[0][3] = fmaf(x0.w, w3.w, acc[0][3]);
            acc[1][0] = fmaf(x1.w, w3.x, acc[1][0]); acc[1][1] = fmaf(x1.w, w3.y, acc[1][1]);
            acc[1][2] = fmaf(x1.w, w3.z, acc[1][2]); acc[1][3] = fmaf(x1.w, w3.w, acc[1][3]);
            acc[2][0] = fmaf(x2.w, w3.x, acc[2][0]); acc[2][1] = fmaf(x2.w, w3.y, acc[2][1]);
            acc[2][2] = fmaf(x2.w, w3.z, acc[2][2]); acc[2][3] = fmaf(x2.w, w3.w, acc[2][3]);
            acc[3][0] = fmaf(x3.w, w3.x, acc[3][0]); acc[3][1] = fmaf(x3.w, w3.y, acc[3][1]);
            acc[3][2] = fmaf(x3.w, w3.z, acc[3][2]); acc[3][3] = fmaf(x3.w, w3.w, acc[3][3]);
        }
        __syncthreads();
    }

#pragma unroll
    for (int j = 0; j < 4; j++) {
        const int row = r0 + rl0 + j;
        if (row < N_NODES) {
            float4 o = make_float4(acc[j][0], acc[j][1], acc[j][2], acc[j][3]);
            *(float4*)&pre[(size_t)row * FOUT + c0] = o;
        }
    }
}

// ---------------------------------------------------------------- bucket count (LDS-aggregated histogram over 782 buckets)
__global__ __launch_bounds__(256) void bcount_kernel(const void* __restrict__ idx0v,
                                                     const void* __restrict__ idx1v,
                                                     int* __restrict__ bcnt,
                                                     const int* __restrict__ flags) {
    __shared__ int h[NB2];
    for (int i = threadIdx.x; i < NB2; i += 256) h[i] = 0;
    __syncthreads();
    const int i64m = flags[1];
    int i = blockIdx.x * 256 + threadIdx.x;
    const int stride = gridDim.x * 256;
    const int total = 2 * E_EDGES;
    for (int e = i; e < total; e += stride) {
        const int s  = (e >= E_EDGES);
        const int ee = e - s * E_EDGES;
        const int* idx32 = (const int*)(s ? idx1v : idx0v);
        int row = i64m ? idx32[2 * (size_t)ee] : idx32[ee];
        atomicAdd(&h[(row >> 7) + s * NB], 1);
    }
    __syncthreads();
    for (int i2 = threadIdx.x; i2 < NB2; i2 += 256) {
        int v = h[i2];
        if (v) atomicAdd(&bcnt[i2], v);
    }
}

// ---------------------------------------------------------------- bucket scan (one block): boffs = exclusive scan, gcur = copy
__global__ __launch_bounds__(1024) void bscan_kernel(const int* __restrict__ bcnt,
                                                     int* __restrict__ boffs,
                                                     int* __restrict__ gcur,
                                                     int* __restrict__ rowoffs) {
    __shared__ int a[1024];
    const int t = threadIdx.x;
    int v = (t < NB2) ? bcnt[t] : 0;
    a[t] = v;
    __syncthreads();
    for (int d = 1; d < 1024; d <<= 1) {
        int u = (t >= d) ? a[t - d] : 0;
        __syncthreads();
        a[t] += u;
        __syncthreads();
    }
    if (t < NB2) {
        int excl = a[t] - v;
        boffs[t] = excl;
        gcur[t]  = excl;
    }
    if (t == 1023) {
        boffs[NB2] = a[1023];
        rowoffs[2 * N_NODES] = a[1023];   // terminator for per-row offsets
    }
}

// ---------------------------------------------------------------- bucket fill: per-block run reservation -> contiguous writes
#define FCHUNK 8192
__global__ __launch_bounds__(256) void bfill_kernel(const void* __restrict__ idx0v, const void* __restrict__ vals0v,
                                                    const void* __restrict__ idx1v, const void* __restrict__ vals1v,
                                                    int* __restrict__ gcur, int2* __restrict__ bucketed,
                                                    const int* __restrict__ flags) {
    __shared__ int cnt[NB2];
    __shared__ int gbase[NB2];
    const int i64m = flags[1];
    const int f32m = flags[0];
    const int tid = threadIdx.x;
    const int c0  = blockIdx.x * FCHUNK;
    const int total = 2 * E_EDGES;

    for (int i = tid; i < NB2; i += 256) cnt[i] = 0;
    __syncthreads();

    // pass 1: local per-bucket counts
#pragma unroll 4
    for (int i = 0; i < FCHUNK / 256; i++) {
        int e = c0 + i * 256 + tid;
        if (e >= total) break;
        const int s  = (e >= E_EDGES);
        const int ee = e - s * E_EDGES;
        const int* idx32 = (const int*)(s ? idx1v : idx0v);
        int row = i64m ? idx32[2 * (size_t)ee] : idx32[ee];
        atomicAdd(&cnt[(row >> 7) + s * NB], 1);
    }
    __syncthreads();

    // reserve a contiguous global run per non-empty bucket
    for (int i = tid; i < NB2; i += 256) {
        int c = cnt[i];
        gbase[i] = c ? atomicAdd(&gcur[i], c) : 0;
    }
    __syncthreads();
    for (int i = tid; i < NB2; i += 256) cnt[i] = 0;  // reuse as local cursor
    __syncthreads();

    // pass 2: scatter into private runs (inputs L2-warm from pass 1)
#pragma unroll 4
    for (int i = 0; i < FCHUNK / 256; i++) {
        int e = c0 + i * 256 + tid;
        if (e >= total) break;
        const int s  = (e >= E_EDGES);
        const int ee = e - s * E_EDGES;
        const int* idx32 = (const int*)(s ? idx1v : idx0v);
        const void* valsv = s ? vals1v : vals0v;
        int row, col;
        if (i64m) {
            row = idx32[2 * (size_t)ee];
            col = idx32[2 * ((size_t)E_EDGES + ee)];
        } else {
            row = idx32[ee];
            col = idx32[E_EDGES + ee];
        }
        float v = f32m ? ((const float*)valsv)[ee] : bf2f(((const ushort*)valsv)[ee]);
        const int b = (row >> 7) + s * NB;
        int lpos = atomicAdd(&cnt[b], 1);
        int2 pr;
        pr.x = col | ((row & (BROWS - 1)) << 16);   // col<2^16, row_local<128
        pr.y = __float_as_int(v);
        bucketed[gbase[b] + lpos] = pr;
    }
}

// ---------------------------------------------------------------- row sort: one block per coarse bucket.
// LDS histogram of the bucket's 128 rows, LDS scan -> per-row offsets,
// scatter pairs row-sorted within the bucket's contiguous window.
__global__ __launch_bounds__(256) void rsort_kernel(
        const int* __restrict__ boffs, const int2* __restrict__ bucketed,
        int2* __restrict__ sorted, int* __restrict__ rowoffs) {
    __shared__ int lcnt[BROWS];
    __shared__ int lscan[BROWS];
    const int tid = threadIdx.x;
    const int cb  = blockIdx.x;               // 0..781
    const int s   = (cb >= NB);
    const int r0  = (cb - s * NB) * BROWS;
    const int beg = boffs[cb];
    const int end = boffs[cb + 1];

    if (tid < BROWS) lcnt[tid] = 0;
    __syncthreads();

    for (int i = beg + tid; i < end; i += 256) {
        int rl = (bucketed[i].x >> 16) & (BROWS - 1);
        atomicAdd(&lcnt[rl], 1);
    }
    __syncthreads();

    // inclusive scan of 128 counts (Hillis-Steele)
    if (tid < BROWS) lscan[tid] = lcnt[tid];
    __syncthreads();
    for (int d = 1; d < BROWS; d <<= 1) {
        int v = 0;
        if (tid < BROWS && tid >= d) v = lscan[tid - d];
        __syncthreads();
        if (tid < BROWS) lscan[tid] += v;
        __syncthreads();
    }
    if (tid < BROWS) {
        int excl = lscan[tid] - lcnt[tid];
        int grow = r0 + tid;
        if (grow < N_NODES)
            rowoffs[(size_t)s * N_NODES + grow] = beg + excl;
        lcnt[tid] = excl;    // reuse as local cursor
    }
    __syncthreads();

    for (int i = beg + tid; i < end; i += 256) {
        int2 pr = bucketed[i];
        int rl = (pr.x >> 16) & (BROWS - 1);
        int pos = beg + atomicAdd(&lcnt[rl], 1);
        sorted[pos] = pr;
    }
}

// ---------------------------------------------------------------- gather: one wave per output row, fused bias+relu+store.
// Inner edge loop unrolled x4 with independent loads: MLP 1 -> 4
// (round-8 fix). Round-9 counters: FETCH pinned at 436 MB, eff. BW
// ~3.9 TB/s -> now bandwidth-bound on the L2-miss path; further ILP
// won't help, only traffic reduction would.
__global__ __launch_bounds__(256) void gather_kernel(
        const float* __restrict__ pre,
        const int* __restrict__ rowoffs, const int2* __restrict__ sorted,
        const void* __restrict__ biasv, void* __restrict__ outv,
        const int* __restrict__ flags) {
    const int w    = (int)((blockIdx.x * blockDim.x + threadIdx.x) >> 6);  // global wave = output row
    const int lane = threadIdx.x & 63;
    if (w >= 2 * N_NODES) return;
    const int beg = rowoffs[w];
    const int end = rowoffs[w + 1];
    const float* prel = pre + lane * 2;

    float a0 = 0.f, a1 = 0.f;
    for (int b = beg; b < end; b += 64) {
        const int kk = min(64, end - b);
        int2 pr; pr.x = 0; pr.y = 0;
        if (lane < kk) pr = sorted[b + lane];
        int j = 0;
        for (; j + 4 <= kk; j += 4) {
            const int c0 = __shfl(pr.x, j)     & 0xFFFF;
            const int c1 = __shfl(pr.x, j + 1) & 0xFFFF;
            const int c2 = __shfl(pr.x, j + 2) & 0xFFFF;
            const int c3 = __shfl(pr.x, j + 3) & 0xFFFF;
            const float v0 = __int_as_float(__shfl(pr.y, j));
            const float v1 = __int_as_float(__shfl(pr.y, j + 1));
            const float v2 = __int_as_float(__shfl(pr.y, j + 2));
            const float v3 = __int_as_float(__shfl(pr.y, j + 3));
            const float2 p0 = *(const float2*)(prel + (size_t)c0 * FOUT);
            const float2 p1 = *(const float2*)(prel + (size_t)c1 * FOUT);
            const float2 p2 = *(const float2*)(prel + (size_t)c2 * FOUT);
            const float2 p3 = *(const float2*)(prel + (size_t)c3 * FOUT);
            a0 = fmaf(v0, p0.x, a0); a1 = fmaf(v0, p0.y, a1);
            a0 = fmaf(v1, p1.x, a0); a1 = fmaf(v1, p1.y, a1);
            a0 = fmaf(v2, p2.x, a0); a1 = fmaf(v2, p2.y, a1);
            a0 = fmaf(v3, p3.x, a0); a1 = fmaf(v3, p3.y, a1);
        }
        for (; j < kk; j++) {
            const int   cj = __shfl(pr.x, j) & 0xFFFF;
            const float vj = __int_as_float(__shfl(pr.y, j));
            const float2 p = *(const float2*)(prel + (size_t)cj * FOUT);
            a0 = fmaf(vj, p.x, a0);
            a1 = fmaf(vj, p.y, a1);
        }
    }

    const int f32m = flags[0];
    float b0, b1;
    if (f32m) {
        const float* bf = (const float*)biasv;
        b0 = bf[lane * 2]; b1 = bf[lane * 2 + 1];
    } else {
        const ushort* bh = (const ushort*)biasv;
        b0 = bf2f(bh[lane * 2]); b1 = bf2f(bh[lane * 2 + 1]);
    }
    const float r0v = fmaxf(a0 + b0, 0.f);
    const float r1v = fmaxf(a1 + b1, 0.f);
    if (f32m) {
        ((float2*)outv)[(size_t)w * 64 + lane] = make_float2(r0v, r1v);
    } else {
        unsigned int o = (unsigned int)f2bf(r0v) | ((unsigned int)f2bf(r1v) << 16);
        ((unsigned int*)outv)[(size_t)w * 64 + lane] = o;
    }
}

extern "C" void kernel_launch(void* const* d_in, const int* in_sizes, int n_in,
                              void* d_out, int out_size, void* d_ws, size_t ws_size,
                              hipStream_t stream) {
    (void)in_sizes; (void)n_in; (void)out_size; (void)ws_size;
    const void* x     = d_in[0];   // [N, FIN] f32 or bf16
    const void* idx0  = d_in[1];   // [2, E] int64 or int32
    const void* vals0 = d_in[2];   // [E]
    const void* idx1  = d_in[3];   // [2, E]
    const void* vals1 = d_in[4];   // [E]
    const void* W     = d_in[5];   // [FIN, FOUT]
    const void* bias  = d_in[6];   // [FOUT]

    char* ws = (char*)d_ws;
    const size_t MB = 1024 * 1024;
    // ws layout:
    //   0        : pre f32 [N*FOUT]            (25.6 MB)
    //   32MB     : bcnt   int[NB2]             (zeroed each call)
    //   32MB+8KB : boffs  int[NB2+1]
    //   32MB+16KB: gcur   int[NB2]
    //   33MB     : rowoffs int[2*N+1]          (400 KB)
    //   40MB     : bucketed int2[2*E] (16 MB)
    //   60MB     : sorted   int2[2*E] (16 MB)
    //   400MB    : flags int[2]
    float* pre      = (float*)ws;
    int*   bcnt     = (int*)(ws + 32 * MB);
    int*   boffs    = (int*)(ws + 32 * MB + 8 * 1024);
    int*   gcur     = (int*)(ws + 32 * MB + 16 * 1024);
    int*   rowoffs  = (int*)(ws + 33 * MB);
    int2*  bucketed = (int2*)(ws + 40 * MB);
    int2*  sorted   = (int2*)(ws + 60 * MB);
    int*   flags    = (int*)(ws + 400 * MB);

    detect_kernel<<<dim3(1), dim3(256), 0, stream>>>(
        (const unsigned int*)x, (const unsigned int*)idx0, flags);
    zero_kernel<<<dim3(1), dim3(256), 0, stream>>>((float4*)bcnt, (NB2 * 4 + 15) / 16);
    gemm_kernel<<<dim3((N_NODES + GBR - 1) / GBR), dim3(256), 0, stream>>>(x, W, pre, flags);
    bcount_kernel<<<dim3(512), dim3(256), 0, stream>>>(idx0, idx1, bcnt, flags);
    bscan_kernel<<<dim3(1), dim3(1024), 0, stream>>>(bcnt, boffs, gcur, rowoffs);
    bfill_kernel<<<dim3((2 * E_EDGES + FCHUNK - 1) / FCHUNK), dim3(256), 0, stream>>>(
        idx0, vals0, idx1, vals1, gcur, bucketed, flags);
    rsort_kernel<<<dim3(NB2), dim3(256), 0, stream>>>(boffs, bucketed, sorted, rowoffs);
    gather_kernel<<<dim3(2 * N_NODES / 4), dim3(256), 0, stream>>>(
        pre, rowoffs, sorted, bias, d_out, flags);
}

// Round 11
// 405.374 us; speedup vs baseline: 1.1417x; 1.1417x over previous
//
#include <hip/hip_runtime.h>
#include <hip/hip_bf16.h>

#define N_NODES 50000
#define E_EDGES 1000000
#define FIN 512
#define FOUT 128

// bucketed CSR: 128 rows per coarse bucket
#define BROWS 128
#define NB 391            // ceil(50000/128) buckets per support
#define NB2 782           // both supports

typedef _Float16 f16;
typedef _Float16 f16x2 __attribute__((ext_vector_type(2)));
typedef _Float16 f16x4 __attribute__((ext_vector_type(4)));

__device__ __forceinline__ float bf2f(unsigned short u) {
    unsigned int x = ((unsigned int)u) << 16;
    return __builtin_bit_cast(float, x);
}
__device__ __forceinline__ unsigned short f2bf(float f) {
    unsigned int x = __builtin_bit_cast(unsigned int, f);
    unsigned int r = x + 0x7fffu + ((x >> 16) & 1u);  // RNE
    return (unsigned short)(r >> 16);
}

// ---------------------------------------------------------------- dtype detection
__global__ void detect_kernel(const unsigned int* __restrict__ xraw,
                              const unsigned int* __restrict__ idxraw,
                              int* __restrict__ flags) {
    __shared__ int cnt, odd_nz;
    const int t = threadIdx.x;
    if (t == 0) { cnt = 0; odd_nz = 0; }
    __syncthreads();
    int local = 0;
    for (int i = t; i < 1024; i += 256) {
        unsigned int b = (xraw[i] >> 7) & 0xFF;   // bits 14..7 = low-half bf16 exponent field
        if (b >= 115 && b <= 133) local++;
    }
    atomicAdd(&cnt, local);
    if (t < 128) {
        if (idxraw[2 * t + 1] != 0u) atomicAdd(&odd_nz, 1);
    }
    __syncthreads();
    if (t == 0) {
        flags[0] = (cnt < 512) ? 1 : 0;   // 1 => floats are f32
        flags[1] = (odd_nz == 0) ? 1 : 0; // 1 => indices are int64
    }
}

// ---------------------------------------------------------------- zero helper
__global__ void zero_kernel(float4* __restrict__ p, int n4) {
    int i = blockIdx.x * blockDim.x + threadIdx.x;
    int stride = gridDim.x * blockDim.x;
    for (; i < n4; i += stride) p[i] = make_float4(0.f, 0.f, 0.f, 0.f);
}

// ---------------------------------------------------------------- GEMM: pre = x @ W, 4x4 register-blocked VALU, dtype-adaptive
// W-staging writes float4 index (tid + 256*j): conflict-free (round-7 fix).
// k4-chunk b128 inner loop (round-9; ~9% on gemm: max(LDS,FMA) 35->32 cyc/k).
// Round-10: pre stored as f16 (f32 accumulate, RNE cvt on store) — halves
// the gather's 512B/row reads; |pre| ~ O(10) << 65504, rel err 2^-11.
#define GBR 32
#define GKT 64
#define SXS 68
__global__ __launch_bounds__(256) void gemm_kernel(const void* __restrict__ xv,
                                                   const void* __restrict__ Wv,
                                                   f16* __restrict__ pre,
                                                   const int* __restrict__ flags) {
    __shared__ float sx[GBR * SXS];   // 8.5 KB
    __shared__ float sw[GKT * FOUT];  // 32 KB

    const int tid  = threadIdx.x;
    const int f32m = flags[0];
    const int r0   = blockIdx.x * GBR;

    const int cg  = tid & 31;         // col group -> 4 cols
    const int rg  = tid >> 5;         // row group 0..7 -> 4 rows
    const int c0  = cg * 4;
    const int rl0 = rg * 4;

    const int lrow  = tid >> 3;           // 0..31
    const int kbase = (tid & 7) * 8;      // 0..56
    int grow = r0 + lrow;
    if (grow >= N_NODES) grow = N_NODES - 1;   // clamp; store is guarded

    float acc[4][4];
#pragma unroll
    for (int j = 0; j < 4; j++)
#pragma unroll
        for (int i = 0; i < 4; i++) acc[j][i] = 0.f;

    for (int kt = 0; kt < FIN; kt += GKT) {
        // ---- stage x tile (32 rows x 64 k)
        if (f32m) {
            const float* xf = (const float*)xv + (size_t)grow * FIN + kt + kbase;
            float4 a = ((const float4*)xf)[0];
            float4 b = ((const float4*)xf)[1];
            *(float4*)&sx[lrow * SXS + kbase]     = a;
            *(float4*)&sx[lrow * SXS + kbase + 4] = b;
        } else {
            const ushort* xh = (const ushort*)xv + (size_t)grow * FIN + kt + kbase;
            ushort tmp[8];
            *(uint4*)tmp = *(const uint4*)xh;
#pragma unroll
            for (int j = 0; j < 8; j++) sx[lrow * SXS + kbase + j] = bf2f(tmp[j]);
        }
        // ---- stage W tile (64 k x 128 cols), conflict-free pattern
        if (f32m) {
            const float4* wf = (const float4*)((const float*)Wv + (size_t)kt * FOUT);
#pragma unroll
            for (int j = 0; j < 8; j++)
                ((float4*)sw)[tid + 256 * j] = wf[tid + 256 * j];
        } else {
            const ushort* wh = (const ushort*)Wv + (size_t)kt * FOUT;
#pragma unroll
            for (int j = 0; j < 8; j++) {
                const int m = tid + 256 * j;          // float4 index
                ushort4 t4 = *(const ushort4*)(wh + 4 * m);
                float4 o;
                o.x = bf2f(t4.x); o.y = bf2f(t4.y);
                o.z = bf2f(t4.z); o.w = bf2f(t4.w);
                ((float4*)sw)[m] = o;
            }
        }
        __syncthreads();

#pragma unroll 2
        for (int kq = 0; kq < GKT / 4; kq++) {
            const int k4 = kq * 4;
            const float4 w0 = *(const float4*)&sw[(k4 + 0) * FOUT + c0];
            const float4 w1 = *(const float4*)&sw[(k4 + 1) * FOUT + c0];
            const float4 w2 = *(const float4*)&sw[(k4 + 2) * FOUT + c0];
            const float4 w3 = *(const float4*)&sw[(k4 + 3) * FOUT + c0];
            const float4 x0 = *(const float4*)&sx[(rl0 + 0) * SXS + k4];
            const float4 x1 = *(const float4*)&sx[(rl0 + 1) * SXS + k4];
            const float4 x2 = *(const float4*)&sx[(rl0 + 2) * SXS + k4];
            const float4 x3 = *(const float4*)&sx[(rl0 + 3) * SXS + k4];
            // dk = 0 (k ascending per accumulator: bit-identical to rolled loop)
            acc[0][0] = fmaf(x0.x, w0.x, acc[0][0]); acc[0][1] = fmaf(x0.x, w0.y, acc[0][1]);
            acc[0][2] = fmaf(x0.x, w0.z, acc[0][2]); acc[0][3] = fmaf(x0.x, w0.w, acc[0][3]);
            acc[1][0] = fmaf(x1.x, w0.x, acc[1][0]); acc[1][1] = fmaf(x1.x, w0.y, acc[1][1]);
            acc[1][2] = fmaf(x1.x, w0.z, acc[1][2]); acc[1][3] = fmaf(x1.x, w0.w, acc[1][3]);
            acc[2][0] = fmaf(x2.x, w0.x, acc[2][0]); acc[2][1] = fmaf(x2.x, w0.y, acc[2][1]);
            acc[2][2] = fmaf(x2.x, w0.z, acc[2][2]); acc[2][3] = fmaf(x2.x, w0.w, acc[2][3]);
            acc[3][0] = fmaf(x3.x, w0.x, acc[3][0]); acc[3][1] = fmaf(x3.x, w0.y, acc[3][1]);
            acc[3][2] = fmaf(x3.x, w0.z, acc[3][2]); acc[3][3] = fmaf(x3.x, w0.w, acc[3][3]);
            // dk = 1
            acc[0][0] = fmaf(x0.y, w1.x, acc[0][0]); acc[0][1] = fmaf(x0.y, w1.y, acc[0][1]);
            acc[0][2] = fmaf(x0.y, w1.z, acc[0][2]); acc[0][3] = fmaf(x0.y, w1.w, acc[0][3]);
            acc[1][0] = fmaf(x1.y, w1.x, acc[1][0]); acc[1][1] = fmaf(x1.y, w1.y, acc[1][1]);
            acc[1][2] = fmaf(x1.y, w1.z, acc[1][2]); acc[1][3] = fmaf(x1.y, w1.w, acc[1][3]);
            acc[2][0] = fmaf(x2.y, w1.x, acc[2][0]); acc[2][1] = fmaf(x2.y, w1.y, acc[2][1]);
            acc[2][2] = fmaf(x2.y, w1.z, acc[2][2]); acc[2][3] = fmaf(x2.y, w1.w, acc[2][3]);
            acc[3][0] = fmaf(x3.y, w1.x, acc[3][0]); acc[3][1] = fmaf(x3.y, w1.y, acc[3][1]);
            acc[3][2] = fmaf(x3.y, w1.z, acc[3][2]); acc[3][3] = fmaf(x3.y, w1.w, acc[3][3]);
            // dk = 2
            acc[0][0] = fmaf(x0.z, w2.x, acc[0][0]); acc[0][1] = fmaf(x0.z, w2.y, acc[0][1]);
            acc[0][2] = fmaf(x0.z, w2.z, acc[0][2]); acc[0][3] = fmaf(x0.z, w2.w, acc[0][3]);
            acc[1][0] = fmaf(x1.z, w2.x, acc[1][0]); acc[1][1] = fmaf(x1.z, w2.y, acc[1][1]);
            acc[1][2] = fmaf(x1.z, w2.z, acc[1][2]); acc[1][3] = fmaf(x1.z, w2.w, acc[1][3]);
            acc[2][0] = fmaf(x2.z, w2.x, acc[2][0]); acc[2][1] = fmaf(x2.z, w2.y, acc[2][1]);
            acc[2][2] = fmaf(x2.z, w2.z, acc[2][2]); acc[2][3] = fmaf(x2.z, w2.w, acc[2][3]);
            acc[3][0] = fmaf(x3.z, w2.x, acc[3][0]); acc[3][1] = fmaf(x3.z, w2.y, acc[3][1]);
            acc[3][2] = fmaf(x3.z, w2.z, acc[3][2]); acc[3][3] = fmaf(x3.z, w2.w, acc[3][3]);
            // dk = 3
            acc[0][0] = fmaf(x0.w, w3.x, acc[0][0]); acc[0][1] = fmaf(x0.w, w3.y, acc[0][1]);
            acc[0][2] = fmaf(x0.w, w3.z, acc[0][2]); acc[0][3] = fmaf(x0.w, w3.w, acc[0][3]);
            acc[1][0] = fmaf(x1.w, w3.x, acc[1][0]); acc[1][1] = fmaf(x1.w, w3.y, acc[1][1]);
            acc[1][2] = fmaf(x1.w, w3.z, acc[1][2]); acc[1][3] = fmaf(x1.w, w3.w, acc[1][3]);
            acc[2][0] = fmaf(x2.w, w3.x, acc[2][0]); acc[2][1] = fmaf(x2.w, w3.y, acc[2][1]);
            acc[2][2] = fmaf(x2.w, w3.z, acc[2][2]); acc[2][3] = fmaf(x2.w, w3.w, acc[2][3]);
            acc[3][0] = fmaf(x3.w, w3.x, acc[3][0]); acc[3][1] = fmaf(x3.w, w3.y, acc[3][1]);
            acc[3][2] = fmaf(x3.w, w3.z, acc[3][2]); acc[3][3] = fmaf(x3.w, w3.w, acc[3][3]);
        }
        __syncthreads();
    }

#pragma unroll
    for (int j = 0; j < 4; j++) {
        const int row = r0 + rl0 + j;
        if (row < N_NODES) {
            f16x4 o;
            o.x = (f16)acc[j][0]; o.y = (f16)acc[j][1];
            o.z = (f16)acc[j][2]; o.w = (f16)acc[j][3];
            *(f16x4*)&pre[(size_t)row * FOUT + c0] = o;   // byte off 256*row+8*cg: 8-aligned
        }
    }
}

// ---------------------------------------------------------------- bucket count (LDS-aggregated histogram over 782 buckets)
__global__ __launch_bounds__(256) void bcount_kernel(const void* __restrict__ idx0v,
                                                     const void* __restrict__ idx1v,
                                                     int* __restrict__ bcnt,
                                                     const int* __restrict__ flags) {
    __shared__ int h[NB2];
    for (int i = threadIdx.x; i < NB2; i += 256) h[i] = 0;
    __syncthreads();
    const int i64m = flags[1];
    int i = blockIdx.x * 256 + threadIdx.x;
    const int stride = gridDim.x * 256;
    const int total = 2 * E_EDGES;
    for (int e = i; e < total; e += stride) {
        const int s  = (e >= E_EDGES);
        const int ee = e - s * E_EDGES;
        const int* idx32 = (const int*)(s ? idx1v : idx0v);
        int row = i64m ? idx32[2 * (size_t)ee] : idx32[ee];
        atomicAdd(&h[(row >> 7) + s * NB], 1);
    }
    __syncthreads();
    for (int i2 = threadIdx.x; i2 < NB2; i2 += 256) {
        int v = h[i2];
        if (v) atomicAdd(&bcnt[i2], v);
    }
}

// ---------------------------------------------------------------- bucket scan (one block): boffs = exclusive scan, gcur = copy
__global__ __launch_bounds__(1024) void bscan_kernel(const int* __restrict__ bcnt,
                                                     int* __restrict__ boffs,
                                                     int* __restrict__ gcur,
                                                     int* __restrict__ rowoffs) {
    __shared__ int a[1024];
    const int t = threadIdx.x;
    int v = (t < NB2) ? bcnt[t] : 0;
    a[t] = v;
    __syncthreads();
    for (int d = 1; d < 1024; d <<= 1) {
        int u = (t >= d) ? a[t - d] : 0;
        __syncthreads();
        a[t] += u;
        __syncthreads();
    }
    if (t < NB2) {
        int excl = a[t] - v;
        boffs[t] = excl;
        gcur[t]  = excl;
    }
    if (t == 1023) {
        boffs[NB2] = a[1023];
        rowoffs[2 * N_NODES] = a[1023];   // terminator for per-row offsets
    }
}

// ---------------------------------------------------------------- bucket fill: per-block run reservation -> contiguous writes
#define FCHUNK 8192
__global__ __launch_bounds__(256) void bfill_kernel(const void* __restrict__ idx0v, const void* __restrict__ vals0v,
                                                    const void* __restrict__ idx1v, const void* __restrict__ vals1v,
                                                    int* __restrict__ gcur, int2* __restrict__ bucketed,
                                                    const int* __restrict__ flags) {
    __shared__ int cnt[NB2];
    __shared__ int gbase[NB2];
    const int i64m = flags[1];
    const int f32m = flags[0];
    const int tid = threadIdx.x;
    const int c0  = blockIdx.x * FCHUNK;
    const int total = 2 * E_EDGES;

    for (int i = tid; i < NB2; i += 256) cnt[i] = 0;
    __syncthreads();

    // pass 1: local per-bucket counts
#pragma unroll 4
    for (int i = 0; i < FCHUNK / 256; i++) {
        int e = c0 + i * 256 + tid;
        if (e >= total) break;
        const int s  = (e >= E_EDGES);
        const int ee = e - s * E_EDGES;
        const int* idx32 = (const int*)(s ? idx1v : idx0v);
        int row = i64m ? idx32[2 * (size_t)ee] : idx32[ee];
        atomicAdd(&cnt[(row >> 7) + s * NB], 1);
    }
    __syncthreads();

    // reserve a contiguous global run per non-empty bucket
    for (int i = tid; i < NB2; i += 256) {
        int c = cnt[i];
        gbase[i] = c ? atomicAdd(&gcur[i], c) : 0;
    }
    __syncthreads();
    for (int i = tid; i < NB2; i += 256) cnt[i] = 0;  // reuse as local cursor
    __syncthreads();

    // pass 2: scatter into private runs (inputs L2-warm from pass 1)
#pragma unroll 4
    for (int i = 0; i < FCHUNK / 256; i++) {
        int e = c0 + i * 256 + tid;
        if (e >= total) break;
        const int s  = (e >= E_EDGES);
        const int ee = e - s * E_EDGES;
        const int* idx32 = (const int*)(s ? idx1v : idx0v);
        const void* valsv = s ? vals1v : vals0v;
        int row, col;
        if (i64m) {
            row = idx32[2 * (size_t)ee];
            col = idx32[2 * ((size_t)E_EDGES + ee)];
        } else {
            row = idx32[ee];
            col = idx32[E_EDGES + ee];
        }
        float v = f32m ? ((const float*)valsv)[ee] : bf2f(((const ushort*)valsv)[ee]);
        const int b = (row >> 7) + s * NB;
        int lpos = atomicAdd(&cnt[b], 1);
        int2 pr;
        pr.x = col | ((row & (BROWS - 1)) << 16);   // col<2^16, row_local<128
        pr.y = __float_as_int(v);
        bucketed[gbase[b] + lpos] = pr;
    }
}

// ---------------------------------------------------------------- row sort: one block per coarse bucket.
// LDS histogram of the bucket's 128 rows, LDS scan -> per-row offsets,
// scatter pairs row-sorted within the bucket's contiguous window.
__global__ __launch_bounds__(256) void rsort_kernel(
        const int* __restrict__ boffs, const int2* __restrict__ bucketed,
        int2* __restrict__ sorted, int* __restrict__ rowoffs) {
    __shared__ int lcnt[BROWS];
    __shared__ int lscan[BROWS];
    const int tid = threadIdx.x;
    const int cb  = blockIdx.x;               // 0..781
    const int s   = (cb >= NB);
    const int r0  = (cb - s * NB) * BROWS;
    const int beg = boffs[cb];
    const int end = boffs[cb + 1];

    if (tid < BROWS) lcnt[tid] = 0;
    __syncthreads();

    for (int i = beg + tid; i < end; i += 256) {
        int rl = (bucketed[i].x >> 16) & (BROWS - 1);
        atomicAdd(&lcnt[rl], 1);
    }
    __syncthreads();

    // inclusive scan of 128 counts (Hillis-Steele)
    if (tid < BROWS) lscan[tid] = lcnt[tid];
    __syncthreads();
    for (int d = 1; d < BROWS; d <<= 1) {
        int v = 0;
        if (tid < BROWS && tid >= d) v = lscan[tid - d];
        __syncthreads();
        if (tid < BROWS) lscan[tid] += v;
        __syncthreads();
    }
    if (tid < BROWS) {
        int excl = lscan[tid] - lcnt[tid];
        int grow = r0 + tid;
        if (grow < N_NODES)
            rowoffs[(size_t)s * N_NODES + grow] = beg + excl;
        lcnt[tid] = excl;    // reuse as local cursor
    }
    __syncthreads();

    for (int i = beg + tid; i < end; i += 256) {
        int2 pr = bucketed[i];
        int rl = (pr.x >> 16) & (BROWS - 1);
        int pos = beg + atomicAdd(&lcnt[rl], 1);
        sorted[pos] = pr;
    }
}

// ---------------------------------------------------------------- gather: one wave per output row, fused bias+relu+store.
// MLP-4 unroll (round-8). Round-10: pre is f16 -> 256B/row instead of
// 512B; the kernel was pinned BW-bound at FETCH=436MB / ~3.9TB/s.
__global__ __launch_bounds__(256) void gather_kernel(
        const f16* __restrict__ pre,
        const int* __restrict__ rowoffs, const int2* __restrict__ sorted,
        const void* __restrict__ biasv, void* __restrict__ outv,
        const int* __restrict__ flags) {
    const int w    = (int)((blockIdx.x * blockDim.x + threadIdx.x) >> 6);  // global wave = output row
    const int lane = threadIdx.x & 63;
    if (w >= 2 * N_NODES) return;
    const int beg = rowoffs[w];
    const int end = rowoffs[w + 1];
    const f16* prel = pre + lane * 2;

    float a0 = 0.f, a1 = 0.f;
    for (int b = beg; b < end; b += 64) {
        const int kk = min(64, end - b);
        int2 pr; pr.x = 0; pr.y = 0;
        if (lane < kk) pr = sorted[b + lane];
        int j = 0;
        for (; j + 4 <= kk; j += 4) {
            const int c0 = __shfl(pr.x, j)     & 0xFFFF;
            const int c1 = __shfl(pr.x, j + 1) & 0xFFFF;
            const int c2 = __shfl(pr.x, j + 2) & 0xFFFF;
            const int c3 = __shfl(pr.x, j + 3) & 0xFFFF;
            const float v0 = __int_as_float(__shfl(pr.y, j));
            const float v1 = __int_as_float(__shfl(pr.y, j + 1));
            const float v2 = __int_as_float(__shfl(pr.y, j + 2));
            const float v3 = __int_as_float(__shfl(pr.y, j + 3));
            const f16x2 p0 = *(const f16x2*)(prel + (size_t)c0 * FOUT);
            const f16x2 p1 = *(const f16x2*)(prel + (size_t)c1 * FOUT);
            const f16x2 p2 = *(const f16x2*)(prel + (size_t)c2 * FOUT);
            const f16x2 p3 = *(const f16x2*)(prel + (size_t)c3 * FOUT);
            a0 = fmaf(v0, (float)p0.x, a0); a1 = fmaf(v0, (float)p0.y, a1);
            a0 = fmaf(v1, (float)p1.x, a0); a1 = fmaf(v1, (float)p1.y, a1);
            a0 = fmaf(v2, (float)p2.x, a0); a1 = fmaf(v2, (float)p2.y, a1);
            a0 = fmaf(v3, (float)p3.x, a0); a1 = fmaf(v3, (float)p3.y, a1);
        }
        for (; j < kk; j++) {
            const int   cj = __shfl(pr.x, j) & 0xFFFF;
            const float vj = __int_as_float(__shfl(pr.y, j));
            const f16x2 p = *(const f16x2*)(prel + (size_t)cj * FOUT);
            a0 = fmaf(vj, (float)p.x, a0);
            a1 = fmaf(vj, (float)p.y, a1);
        }
    }

    const int f32m = flags[0];
    float b0, b1;
    if (f32m) {
        const float* bf = (const float*)biasv;
        b0 = bf[lane * 2]; b1 = bf[lane * 2 + 1];
    } else {
        const ushort* bh = (const ushort*)biasv;
        b0 = bf2f(bh[lane * 2]); b1 = bf2f(bh[lane * 2 + 1]);
    }
    const float r0v = fmaxf(a0 + b0, 0.f);
    const float r1v = fmaxf(a1 + b1, 0.f);
    if (f32m) {
        ((float2*)outv)[(size_t)w * 64 + lane] = make_float2(r0v, r1v);
    } else {
        unsigned int o = (unsigned int)f2bf(r0v) | ((unsigned int)f2bf(r1v) << 16);
        ((unsigned int*)outv)[(size_t)w * 64 + lane] = o;
    }
}

extern "C" void kernel_launch(void* const* d_in, const int* in_sizes, int n_in,
                              void* d_out, int out_size, void* d_ws, size_t ws_size,
                              hipStream_t stream) {
    (void)in_sizes; (void)n_in; (void)out_size; (void)ws_size;
    const void* x     = d_in[0];   // [N, FIN] f32 or bf16
    const void* idx0  = d_in[1];   // [2, E] int64 or int32
    const void* vals0 = d_in[2];   // [E]
    const void* idx1  = d_in[3];   // [2, E]
    const void* vals1 = d_in[4];   // [E]
    const void* W     = d_in[5];   // [FIN, FOUT]
    const void* bias  = d_in[6];   // [FOUT]

    char* ws = (char*)d_ws;
    const size_t MB = 1024 * 1024;
    // ws layout:
    //   0        : pre f16 [N*FOUT]            (12.8 MB)
    //   32MB     : bcnt   int[NB2]             (zeroed each call)
    //   32MB+8KB : boffs  int[NB2+1]
    //   32MB+16KB: gcur   int[NB2]
    //   33MB     : rowoffs int[2*N+1]          (400 KB)
    //   40MB     : bucketed int2[2*E] (16 MB)
    //   60MB     : sorted   int2[2*E] (16 MB)
    //   400MB    : flags int[2]
    f16*   pre      = (f16*)ws;
    int*   bcnt     = (int*)(ws + 32 * MB);
    int*   boffs    = (int*)(ws + 32 * MB + 8 * 1024);
    int*   gcur     = (int*)(ws + 32 * MB + 16 * 1024);
    int*   rowoffs  = (int*)(ws + 33 * MB);
    int2*  bucketed = (int2*)(ws + 40 * MB);
    int2*  sorted   = (int2*)(ws + 60 * MB);
    int*   flags    = (int*)(ws + 400 * MB);

    detect_kernel<<<dim3(1), dim3(256), 0, stream>>>(
        (const unsigned int*)x, (const unsigned int*)idx0, flags);
    zero_kernel<<<dim3(1), dim3(256), 0, stream>>>((float4*)bcnt, (NB2 * 4 + 15) / 16);
    gemm_kernel<<<dim3((N_NODES + GBR - 1) / GBR), dim3(256), 0, stream>>>(x, W, pre, flags);
    bcount_kernel<<<dim3(512), dim3(256), 0, stream>>>(idx0, idx1, bcnt, flags);
    bscan_kernel<<<dim3(1), dim3(1024), 0, stream>>>(bcnt, boffs, gcur, rowoffs);
    bfill_kernel<<<dim3((2 * E_EDGES + FCHUNK - 1) / FCHUNK), dim3(256), 0, stream>>>(
        idx0, vals0, idx1, vals1, gcur, bucketed, flags);
    rsort_kernel<<<dim3(NB2), dim3(256), 0, stream>>>(boffs, bucketed, sorted, rowoffs);
    gather_kernel<<<dim3(2 * N_NODES / 4), dim3(256), 0, stream>>>(
        pre, rowoffs, sorted, bias, d_out, flags);
}

// Round 12
// 403.489 us; speedup vs baseline: 1.1471x; 1.0047x over previous
//
#include <hip/hip_runtime.h>
#include <hip/hip_bf16.h>

#define N_NODES 50000
#define E_EDGES 1000000
#define FIN 512
#define FOUT 128

// bucketed CSR: 128 rows per coarse bucket
#define BROWS 128
#define NB 391            // ceil(50000/128) buckets per support
#define NB2 782           // both supports

typedef _Float16 f16;
typedef _Float16 f16x2 __attribute__((ext_vector_type(2)));
typedef _Float16 f16x4 __attribute__((ext_vector_type(4)));

__device__ __forceinline__ float bf2f(unsigned short u) {
    unsigned int x = ((unsigned int)u) << 16;
    return __builtin_bit_cast(float, x);
}
__device__ __forceinline__ unsigned short f2bf(float f) {
    unsigned int x = __builtin_bit_cast(unsigned int, f);
    unsigned int r = x + 0x7fffu + ((x >> 16) & 1u);  // RNE
    return (unsigned short)(r >> 16);
}

// ---------------------------------------------------------------- dtype detection
__global__ void detect_kernel(const unsigned int* __restrict__ xraw,
                              const unsigned int* __restrict__ idxraw,
                              int* __restrict__ flags) {
    __shared__ int cnt, odd_nz;
    const int t = threadIdx.x;
    if (t == 0) { cnt = 0; odd_nz = 0; }
    __syncthreads();
    int local = 0;
    for (int i = t; i < 1024; i += 256) {
        unsigned int b = (xraw[i] >> 7) & 0xFF;   // bits 14..7 = low-half bf16 exponent field
        if (b >= 115 && b <= 133) local++;
    }
    atomicAdd(&cnt, local);
    if (t < 128) {
        if (idxraw[2 * t + 1] != 0u) atomicAdd(&odd_nz, 1);
    }
    __syncthreads();
    if (t == 0) {
        flags[0] = (cnt < 512) ? 1 : 0;   // 1 => floats are f32
        flags[1] = (odd_nz == 0) ? 1 : 0; // 1 => indices are int64
    }
}

// ---------------------------------------------------------------- zero helper
__global__ void zero_kernel(float4* __restrict__ p, int n4) {
    int i = blockIdx.x * blockDim.x + threadIdx.x;
    int stride = gridDim.x * blockDim.x;
    for (; i < n4; i += stride) p[i] = make_float4(0.f, 0.f, 0.f, 0.f);
}

// ---------------------------------------------------------------- GEMM: pre = x @ W, 4x4 register-blocked VALU, dtype-adaptive
// Round-7: conflict-free W staging (tid + 256*j).
// Round-9: k4-chunk b128 reads.
// Round-10: pre stored f16 (f32 accumulate), halves gather traffic.
// Round-11: GKT 64->32 (LDS 41.5 -> 20.6 KB) + __launch_bounds__(256,4)
// (VGPR<=64): occupancy was 24% (2 blocks/CU, LDS+VGPR-capped) and the
// kernel was stall-bound (VALUBusy 46%, FMA floor 42us vs 120us actual).
#define GBR 32
#define GKT 32
#define SXS 36
__global__ __launch_bounds__(256, 4) void gemm_kernel(const void* __restrict__ xv,
                                                      const void* __restrict__ Wv,
                                                      f16* __restrict__ pre,
                                                      const int* __restrict__ flags) {
    __shared__ float sx[GBR * SXS];   // 4.6 KB
    __shared__ float sw[GKT * FOUT];  // 16 KB

    const int tid  = threadIdx.x;
    const int f32m = flags[0];
    const int r0   = blockIdx.x * GBR;

    const int cg  = tid & 31;         // col group -> 4 cols
    const int rg  = tid >> 5;         // row group 0..7 -> 4 rows
    const int c0  = cg * 4;
    const int rl0 = rg * 4;

    const int lrow  = tid >> 3;           // 0..31
    const int kbase = (tid & 7) * 4;      // 0..28
    int grow = r0 + lrow;
    if (grow >= N_NODES) grow = N_NODES - 1;   // clamp; store is guarded

    float acc[4][4];
#pragma unroll
    for (int j = 0; j < 4; j++)
#pragma unroll
        for (int i = 0; i < 4; i++) acc[j][i] = 0.f;

    for (int kt = 0; kt < FIN; kt += GKT) {
        // ---- stage x tile (32 rows x 32 k): 1 float4 / thread
        if (f32m) {
            const float* xf = (const float*)xv + (size_t)grow * FIN + kt + kbase;
            *(float4*)&sx[lrow * SXS + kbase] = *(const float4*)xf;
        } else {
            const ushort* xh = (const ushort*)xv + (size_t)grow * FIN + kt + kbase;
            ushort tmp[4];
            *(uint2*)tmp = *(const uint2*)xh;
#pragma unroll
            for (int j = 0; j < 4; j++) sx[lrow * SXS + kbase + j] = bf2f(tmp[j]);
        }
        // ---- stage W tile (32 k x 128 cols), conflict-free pattern
        if (f32m) {
            const float4* wf = (const float4*)((const float*)Wv + (size_t)kt * FOUT);
#pragma unroll
            for (int j = 0; j < 4; j++)
                ((float4*)sw)[tid + 256 * j] = wf[tid + 256 * j];
        } else {
            const ushort* wh = (const ushort*)Wv + (size_t)kt * FOUT;
#pragma unroll
            for (int j = 0; j < 4; j++) {
                const int m = tid + 256 * j;          // float4 index
                ushort4 t4 = *(const ushort4*)(wh + 4 * m);
                float4 o;
                o.x = bf2f(t4.x); o.y = bf2f(t4.y);
                o.z = bf2f(t4.z); o.w = bf2f(t4.w);
                ((float4*)sw)[m] = o;
            }
        }
        __syncthreads();

#pragma unroll 2
        for (int kq = 0; kq < GKT / 4; kq++) {
            const int k4 = kq * 4;
            const float4 w0 = *(const float4*)&sw[(k4 + 0) * FOUT + c0];
            const float4 w1 = *(const float4*)&sw[(k4 + 1) * FOUT + c0];
            const float4 w2 = *(const float4*)&sw[(k4 + 2) * FOUT + c0];
            const float4 w3 = *(const float4*)&sw[(k4 + 3) * FOUT + c0];
            const float4 x0 = *(const float4*)&sx[(rl0 + 0) * SXS + k4];
            const float4 x1 = *(const float4*)&sx[(rl0 + 1) * SXS + k4];
            const float4 x2 = *(const float4*)&sx[(rl0 + 2) * SXS + k4];
            const float4 x3 = *(const float4*)&sx[(rl0 + 3) * SXS + k4];
            // dk = 0 (k ascending per accumulator: bit-identical ordering)
            acc[0][0] = fmaf(x0.x, w0.x, acc[0][0]); acc[0][1] = fmaf(x0.x, w0.y, acc[0][1]);
            acc[0][2] = fmaf(x0.x, w0.z, acc[0][2]); acc[0][3] = fmaf(x0.x, w0.w, acc[0][3]);
            acc[1][0] = fmaf(x1.x, w0.x, acc[1][0]); acc[1][1] = fmaf(x1.x, w0.y, acc[1][1]);
            acc[1][2] = fmaf(x1.x, w0.z, acc[1][2]); acc[1][3] = fmaf(x1.x, w0.w, acc[1][3]);
            acc[2][0] = fmaf(x2.x, w0.x, acc[2][0]); acc[2][1] = fmaf(x2.x, w0.y, acc[2][1]);
            acc[2][2] = fmaf(x2.x, w0.z, acc[2][2]); acc[2][3] = fmaf(x2.x, w0.w, acc[2][3]);
            acc[3][0] = fmaf(x3.x, w0.x, acc[3][0]); acc[3][1] = fmaf(x3.x, w0.y, acc[3][1]);
            acc[3][2] = fmaf(x3.x, w0.z, acc[3][2]); acc[3][3] = fmaf(x3.x, w0.w, acc[3][3]);
            // dk = 1
            acc[0][0] = fmaf(x0.y, w1.x, acc[0][0]); acc[0][1] = fmaf(x0.y, w1.y, acc[0][1]);
            acc[0][2] = fmaf(x0.y, w1.z, acc[0][2]); acc[0][3] = fmaf(x0.y, w1.w, acc[0][3]);
            acc[1][0] = fmaf(x1.y, w1.x, acc[1][0]); acc[1][1] = fmaf(x1.y, w1.y, acc[1][1]);
            acc[1][2] = fmaf(x1.y, w1.z, acc[1][2]); acc[1][3] = fmaf(x1.y, w1.w, acc[1][3]);
            acc[2][0] = fmaf(x2.y, w1.x, acc[2][0]); acc[2][1] = fmaf(x2.y, w1.y, acc[2][1]);
            acc[2][2] = fmaf(x2.y, w1.z, acc[2][2]); acc[2][3] = fmaf(x2.y, w1.w, acc[2][3]);
            acc[3][0] = fmaf(x3.y, w1.x, acc[3][0]); acc[3][1] = fmaf(x3.y, w1.y, acc[3][1]);
            acc[3][2] = fmaf(x3.y, w1.z, acc[3][2]); acc[3][3] = fmaf(x3.y, w1.w, acc[3][3]);
            // dk = 2
            acc[0][0] = fmaf(x0.z, w2.x, acc[0][0]); acc[0][1] = fmaf(x0.z, w2.y, acc[0][1]);
            acc[0][2] = fmaf(x0.z, w2.z, acc[0][2]); acc[0][3] = fmaf(x0.z, w2.w, acc[0][3]);
            acc[1][0] = fmaf(x1.z, w2.x, acc[1][0]); acc[1][1] = fmaf(x1.z, w2.y, acc[1][1]);
            acc[1][2] = fmaf(x1.z, w2.z, acc[1][2]); acc[1][3] = fmaf(x1.z, w2.w, acc[1][3]);
            acc[2][0] = fmaf(x2.z, w2.x, acc[2][0]); acc[2][1] = fmaf(x2.z, w2.y, acc[2][1]);
            acc[2][2] = fmaf(x2.z, w2.z, acc[2][2]); acc[2][3] = fmaf(x2.z, w2.w, acc[2][3]);
            acc[3][0] = fmaf(x3.z, w2.x, acc[3][0]); acc[3][1] = fmaf(x3.z, w2.y, acc[3][1]);
            acc[3][2] = fmaf(x3.z, w2.z, acc[3][2]); acc[3][3] = fmaf(x3.z, w2.w, acc[3][3]);
            // dk = 3
            acc[0][0] = fmaf(x0.w, w3.x, acc[0][0]); acc[0][1] = fmaf(x0.w, w3.y, acc[0][1]);
            acc[0][2] = fmaf(x0.w, w3.z, acc[0][2]); acc[0][3] = fmaf(x0.w, w3.w, acc[0][3]);
            acc[1][0] = fmaf(x1.w, w3.x, acc[1][0]); acc[1][1] = fmaf(x1.w, w3.y, acc[1][1]);
            acc[1][2] = fmaf(x1.w, w3.z, acc[1][2]); acc[1][3] = fmaf(x1.w, w3.w, acc[1][3]);
            acc[2][0] = fmaf(x2.w, w3.x, acc[2][0]); acc[2][1] = fmaf(x2.w, w3.y, acc[2][1]);
            acc[2][2] = fmaf(x2.w, w3.z, acc[2][2]); acc[2][3] = fmaf(x2.w, w3.w, acc[2][3]);
            acc[3][0] = fmaf(x3.w, w3.x, acc[3][0]); acc[3][1] = fmaf(x3.w, w3.y, acc[3][1]);
            acc[3][2] = fmaf(x3.w, w3.z, acc[3][2]); acc[3][3] = fmaf(x3.w, w3.w, acc[3][3]);
        }
        __syncthreads();
    }

#pragma unroll
    for (int j = 0; j < 4; j++) {
        const int row = r0 + rl0 + j;
        if (row < N_NODES) {
            f16x4 o;
            o.x = (f16)acc[j][0]; o.y = (f16)acc[j][1];
            o.z = (f16)acc[j][2]; o.w = (f16)acc[j][3];
            *(f16x4*)&pre[(size_t)row * FOUT + c0] = o;   // byte off 256*row+8*cg: 8-aligned
        }
    }
}

// ---------------------------------------------------------------- bucket count (LDS-aggregated histogram over 782 buckets)
__global__ __launch_bounds__(256) void bcount_kernel(const void* __restrict__ idx0v,
                                                     const void* __restrict__ idx1v,
                                                     int* __restrict__ bcnt,
                                                     const int* __restrict__ flags) {
    __shared__ int h[NB2];
    for (int i = threadIdx.x; i < NB2; i += 256) h[i] = 0;
    __syncthreads();
    const int i64m = flags[1];
    int i = blockIdx.x * 256 + threadIdx.x;
    const int stride = gridDim.x * 256;
    const int total = 2 * E_EDGES;
    for (int e = i; e < total; e += stride) {
        const int s  = (e >= E_EDGES);
        const int ee = e - s * E_EDGES;
        const int* idx32 = (const int*)(s ? idx1v : idx0v);
        int row = i64m ? idx32[2 * (size_t)ee] : idx32[ee];
        atomicAdd(&h[(row >> 7) + s * NB], 1);
    }
    __syncthreads();
    for (int i2 = threadIdx.x; i2 < NB2; i2 += 256) {
        int v = h[i2];
        if (v) atomicAdd(&bcnt[i2], v);
    }
}

// ---------------------------------------------------------------- bucket scan (one block): boffs = exclusive scan, gcur = copy
__global__ __launch_bounds__(1024) void bscan_kernel(const int* __restrict__ bcnt,
                                                     int* __restrict__ boffs,
                                                     int* __restrict__ gcur,
                                                     int* __restrict__ rowoffs) {
    __shared__ int a[1024];
    const int t = threadIdx.x;
    int v = (t < NB2) ? bcnt[t] : 0;
    a[t] = v;
    __syncthreads();
    for (int d = 1; d < 1024; d <<= 1) {
        int u = (t >= d) ? a[t - d] : 0;
        __syncthreads();
        a[t] += u;
        __syncthreads();
    }
    if (t < NB2) {
        int excl = a[t] - v;
        boffs[t] = excl;
        gcur[t]  = excl;
    }
    if (t == 1023) {
        boffs[NB2] = a[1023];
        rowoffs[2 * N_NODES] = a[1023];   // terminator for per-row offsets
    }
}

// ---------------------------------------------------------------- bucket fill: per-block run reservation -> contiguous writes
#define FCHUNK 8192
__global__ __launch_bounds__(256) void bfill_kernel(const void* __restrict__ idx0v, const void* __restrict__ vals0v,
                                                    const void* __restrict__ idx1v, const void* __restrict__ vals1v,
                                                    int* __restrict__ gcur, int2* __restrict__ bucketed,
                                                    const int* __restrict__ flags) {
    __shared__ int cnt[NB2];
    __shared__ int gbase[NB2];
    const int i64m = flags[1];
    const int f32m = flags[0];
    const int tid = threadIdx.x;
    const int c0  = blockIdx.x * FCHUNK;
    const int total = 2 * E_EDGES;

    for (int i = tid; i < NB2; i += 256) cnt[i] = 0;
    __syncthreads();

    // pass 1: local per-bucket counts
#pragma unroll 4
    for (int i = 0; i < FCHUNK / 256; i++) {
        int e = c0 + i * 256 + tid;
        if (e >= total) break;
        const int s  = (e >= E_EDGES);
        const int ee = e - s * E_EDGES;
        const int* idx32 = (const int*)(s ? idx1v : idx0v);
        int row = i64m ? idx32[2 * (size_t)ee] : idx32[ee];
        atomicAdd(&cnt[(row >> 7) + s * NB], 1);
    }
    __syncthreads();

    // reserve a contiguous global run per non-empty bucket
    for (int i = tid; i < NB2; i += 256) {
        int c = cnt[i];
        gbase[i] = c ? atomicAdd(&gcur[i], c) : 0;
    }
    __syncthreads();
    for (int i = tid; i < NB2; i += 256) cnt[i] = 0;  // reuse as local cursor
    __syncthreads();

    // pass 2: scatter into private runs (inputs L2-warm from pass 1)
#pragma unroll 4
    for (int i = 0; i < FCHUNK / 256; i++) {
        int e = c0 + i * 256 + tid;
        if (e >= total) break;
        const int s  = (e >= E_EDGES);
        const int ee = e - s * E_EDGES;
        const int* idx32 = (const int*)(s ? idx1v : idx0v);
        const void* valsv = s ? vals1v : vals0v;
        int row, col;
        if (i64m) {
            row = idx32[2 * (size_t)ee];
            col = idx32[2 * ((size_t)E_EDGES + ee)];
        } else {
            row = idx32[ee];
            col = idx32[E_EDGES + ee];
        }
        float v = f32m ? ((const float*)valsv)[ee] : bf2f(((const ushort*)valsv)[ee]);
        const int b = (row >> 7) + s * NB;
        int lpos = atomicAdd(&cnt[b], 1);
        int2 pr;
        pr.x = col | ((row & (BROWS - 1)) << 16);   // col<2^16, row_local<128
        pr.y = __float_as_int(v);
        bucketed[gbase[b] + lpos] = pr;
    }
}

// ---------------------------------------------------------------- row sort: one block per coarse bucket.
// LDS histogram of the bucket's 128 rows, LDS scan -> per-row offsets,
// scatter pairs row-sorted within the bucket's contiguous window.
__global__ __launch_bounds__(256) void rsort_kernel(
        const int* __restrict__ boffs, const int2* __restrict__ bucketed,
        int2* __restrict__ sorted, int* __restrict__ rowoffs) {
    __shared__ int lcnt[BROWS];
    __shared__ int lscan[BROWS];
    const int tid = threadIdx.x;
    const int cb  = blockIdx.x;               // 0..781
    const int s   = (cb >= NB);
    const int r0  = (cb - s * NB) * BROWS;
    const int beg = boffs[cb];
    const int end = boffs[cb + 1];

    if (tid < BROWS) lcnt[tid] = 0;
    __syncthreads();

    for (int i = beg + tid; i < end; i += 256) {
        int rl = (bucketed[i].x >> 16) & (BROWS - 1);
        atomicAdd(&lcnt[rl], 1);
    }
    __syncthreads();

    // inclusive scan of 128 counts (Hillis-Steele)
    if (tid < BROWS) lscan[tid] = lcnt[tid];
    __syncthreads();
    for (int d = 1; d < BROWS; d <<= 1) {
        int v = 0;
        if (tid < BROWS && tid >= d) v = lscan[tid - d];
        __syncthreads();
        if (tid < BROWS) lscan[tid] += v;
        __syncthreads();
    }
    if (tid < BROWS) {
        int excl = lscan[tid] - lcnt[tid];
        int grow = r0 + tid;
        if (grow < N_NODES)
            rowoffs[(size_t)s * N_NODES + grow] = beg + excl;
        lcnt[tid] = excl;    // reuse as local cursor
    }
    __syncthreads();

    for (int i = beg + tid; i < end; i += 256) {
        int2 pr = bucketed[i];
        int rl = (pr.x >> 16) & (BROWS - 1);
        int pos = beg + atomicAdd(&lcnt[rl], 1);
        sorted[pos] = pr;
    }
}

// ---------------------------------------------------------------- gather: one wave per output row, fused bias+relu+store.
// MLP-4 unroll (round-8); f16 pre (round-10): BW-bound on L2-miss path.
__global__ __launch_bounds__(256) void gather_kernel(
        const f16* __restrict__ pre,
        const int* __restrict__ rowoffs, const int2* __restrict__ sorted,
        const void* __restrict__ biasv, void* __restrict__ outv,
        const int* __restrict__ flags) {
    const int w    = (int)((blockIdx.x * blockDim.x + threadIdx.x) >> 6);  // global wave = output row
    const int lane = threadIdx.x & 63;
    if (w >= 2 * N_NODES) return;
    const int beg = rowoffs[w];
    const int end = rowoffs[w + 1];
    const f16* prel = pre + lane * 2;

    float a0 = 0.f, a1 = 0.f;
    for (int b = beg; b < end; b += 64) {
        const int kk = min(64, end - b);
        int2 pr; pr.x = 0; pr.y = 0;
        if (lane < kk) pr = sorted[b + lane];
        int j = 0;
        for (; j + 4 <= kk; j += 4) {
            const int c0 = __shfl(pr.x, j)     & 0xFFFF;
            const int c1 = __shfl(pr.x, j + 1) & 0xFFFF;
            const int c2 = __shfl(pr.x, j + 2) & 0xFFFF;
            const int c3 = __shfl(pr.x, j + 3) & 0xFFFF;
            const float v0 = __int_as_float(__shfl(pr.y, j));
            const float v1 = __int_as_float(__shfl(pr.y, j + 1));
            const float v2 = __int_as_float(__shfl(pr.y, j + 2));
            const float v3 = __int_as_float(__shfl(pr.y, j + 3));
            const f16x2 p0 = *(const f16x2*)(prel + (size_t)c0 * FOUT);
            const f16x2 p1 = *(const f16x2*)(prel + (size_t)c1 * FOUT);
            const f16x2 p2 = *(const f16x2*)(prel + (size_t)c2 * FOUT);
            const f16x2 p3 = *(const f16x2*)(prel + (size_t)c3 * FOUT);
            a0 = fmaf(v0, (float)p0.x, a0); a1 = fmaf(v0, (float)p0.y, a1);
            a0 = fmaf(v1, (float)p1.x, a0); a1 = fmaf(v1, (float)p1.y, a1);
            a0 = fmaf(v2, (float)p2.x, a0); a1 = fmaf(v2, (float)p2.y, a1);
            a0 = fmaf(v3, (float)p3.x, a0); a1 = fmaf(v3, (float)p3.y, a1);
        }
        for (; j < kk; j++) {
            const int   cj = __shfl(pr.x, j) & 0xFFFF;
            const float vj = __int_as_float(__shfl(pr.y, j));
            const f16x2 p = *(const f16x2*)(prel + (size_t)cj * FOUT);
            a0 = fmaf(vj, (float)p.x, a0);
            a1 = fmaf(vj, (float)p.y, a1);
        }
    }

    const int f32m = flags[0];
    float b0, b1;
    if (f32m) {
        const float* bf = (const float*)biasv;
        b0 = bf[lane * 2]; b1 = bf[lane * 2 + 1];
    } else {
        const ushort* bh = (const ushort*)biasv;
        b0 = bf2f(bh[lane * 2]); b1 = bf2f(bh[lane * 2 + 1]);
    }
    const float r0v = fmaxf(a0 + b0, 0.f);
    const float r1v = fmaxf(a1 + b1, 0.f);
    if (f32m) {
        ((float2*)outv)[(size_t)w * 64 + lane] = make_float2(r0v, r1v);
    } else {
        unsigned int o = (unsigned int)f2bf(r0v) | ((unsigned int)f2bf(r1v) << 16);
        ((unsigned int*)outv)[(size_t)w * 64 + lane] = o;
    }
}

extern "C" void kernel_launch(void* const* d_in, const int* in_sizes, int n_in,
                              void* d_out, int out_size, void* d_ws, size_t ws_size,
                              hipStream_t stream) {
    (void)in_sizes; (void)n_in; (void)out_size; (void)ws_size;
    const void* x     = d_in[0];   // [N, FIN] f32 or bf16
    const void* idx0  = d_in[1];   // [2, E] int64 or int32
    const void* vals0 = d_in[2];   // [E]
    const void* idx1  = d_in[3];   // [2, E]
    const void* vals1 = d_in[4];   // [E]
    const void* W     = d_in[5];   // [FIN, FOUT]
    const void* bias  = d_in[6];   // [FOUT]

    char* ws = (char*)d_ws;
    const size_t MB = 1024 * 1024;
    // ws layout:
    //   0        : pre f16 [N*FOUT]            (12.8 MB)
    //   32MB     : bcnt   int[NB2]             (zeroed each call)
    //   32MB+8KB : boffs  int[NB2+1]
    //   32MB+16KB: gcur   int[NB2]
    //   33MB     : rowoffs int[2*N+1]          (400 KB)
    //   40MB     : bucketed int2[2*E] (16 MB)
    //   60MB     : sorted   int2[2*E] (16 MB)
    //   400MB    : flags int[2]
    f16*   pre      = (f16*)ws;
    int*   bcnt     = (int*)(ws + 32 * MB);
    int*   boffs    = (int*)(ws + 32 * MB + 8 * 1024);
    int*   gcur     = (int*)(ws + 32 * MB + 16 * 1024);
    int*   rowoffs  = (int*)(ws + 33 * MB);
    int2*  bucketed = (int2*)(ws + 40 * MB);
    int2*  sorted   = (int2*)(ws + 60 * MB);
    int*   flags    = (int*)(ws + 400 * MB);

    detect_kernel<<<dim3(1), dim3(256), 0, stream>>>(
        (const unsigned int*)x, (const unsigned int*)idx0, flags);
    zero_kernel<<<dim3(1), dim3(256), 0, stream>>>((float4*)bcnt, (NB2 * 4 + 15) / 16);
    gemm_kernel<<<dim3((N_NODES + GBR - 1) / GBR), dim3(256), 0, stream>>>(x, W, pre, flags);
    bcount_kernel<<<dim3(512), dim3(256), 0, stream>>>(idx0, idx1, bcnt, flags);
    bscan_kernel<<<dim3(1), dim3(1024), 0, stream>>>(bcnt, boffs, gcur, rowoffs);
    bfill_kernel<<<dim3((2 * E_EDGES + FCHUNK - 1) / FCHUNK), dim3(256), 0, stream>>>(
        idx0, vals0, idx1, vals1, gcur, bucketed, flags);
    rsort_kernel<<<dim3(NB2), dim3(256), 0, stream>>>(boffs, bucketed, sorted, rowoffs);
    gather_kernel<<<dim3(2 * N_NODES / 4), dim3(256), 0, stream>>>(
        pre, rowoffs, sorted, bias, d_out, flags);
}